// Round 3
// baseline (1023.913 us; speedup 1.0000x reference)
//
#include <hip/hip_runtime.h>
#include <stdint.h>

#define B    16384
#define G    128
#define SMAX 64
#define H    10
#define PH   100

// ---------------------------------------------------------------------------
// Kernel 1: per-gene MLP -> glT[g][b].
// Stage: block cooperatively loads x[b0:b0+256][g][0:64] with 16 lanes per
// row (256B fully-consumed contiguous chunks, 4 rows per wave-instruction)
// via global_load_lds (width 16). LDS layout [256][64] unpadded so the LDS
// dest is exactly base + lane*16 (wave-uniform-dest requirement). Bank
// conflicts on readback are fixed by pre-permuting the GLOBAL source chunk
// (csrc = col ^ (sub&7)) and XOR-swizzling the ds_read_b128 address -> even
// 8-access-per-bank = b128 floor.
// Compute: thread t owns row t; weights are wave-uniform (g=blockIdx.y) ->
// scalar loads feed v_fmac directly.
// Grid: (B/256, G). Block: 256.
// ---------------------------------------------------------------------------
__global__ __launch_bounds__(256) void gene_kernel(
    const float* __restrict__ x,  const float* __restrict__ W1,
    const float* __restrict__ b1, const float* __restrict__ W2,
    const float* __restrict__ b2, float* __restrict__ glT)
{
    __shared__ float sX[256][SMAX];   // 64 KiB, unpadded (gll dest = lane*16)

    const int tid = threadIdx.x;
    const int g   = blockIdx.y;
    const int b0  = blockIdx.x * 256;

    const int sub  = tid >> 4;               // row-within-group 0..15
    const int col  = tid & 15;               // float4 slot 0..15
    const int csrc = col ^ (sub & 7);        // source-permute (swizzle, r&7 = sub&7)

    // Global source: row (b0 + sub + 16k), chunk csrc. 16 lanes cover 256B.
    const float* gbase = x + ((size_t)(b0 + sub) * G + g) * SMAX + csrc * 4;
    char* lbase = (char*)&sX[0][0] + tid * 16;

    #pragma unroll
    for (int k = 0; k < 16; k++) {
        __builtin_amdgcn_global_load_lds(
            (const __attribute__((address_space(1))) uint32_t*)
                (gbase + (size_t)k * 16 * G * SMAX),
            (__attribute__((address_space(3))) uint32_t*)(lbase + k * 4096),
            16, 0, 0);
    }
    __syncthreads();   // drains vmcnt before barrier

    // Wave-uniform weight base -> scalar loads, constant offsets.
    const float* __restrict__ w1g = W1 + (size_t)g * SMAX * H;

    float acc[H];
    #pragma unroll
    for (int j = 0; j < H; j++) acc[j] = b1[g * H + j];

    const int rsw = tid & 7;                 // read-side swizzle key
    #pragma unroll
    for (int i = 0; i < 16; i++) {
        const int p = i ^ rsw;               // physical float4 slot
        const float4 xv = *(const float4*)&sX[tid][p * 4];
        const float xs0 = xv.x, xs1 = xv.y, xs2 = xv.z, xs3 = xv.w;
        #pragma unroll
        for (int j = 0; j < H; j++) {
            float a = acc[j];
            a = fmaf(xs0, w1g[(i * 4 + 0) * H + j], a);
            a = fmaf(xs1, w1g[(i * 4 + 1) * H + j], a);
            a = fmaf(xs2, w1g[(i * 4 + 2) * H + j], a);
            a = fmaf(xs3, w1g[(i * 4 + 3) * H + j], a);
            acc[j] = a;
        }
    }

    float gene = b2[g];
    #pragma unroll
    for (int j = 0; j < H; j++) {
        gene += fmaxf(acc[j], 0.f) * W2[g * H + j];
    }

    glT[(size_t)g * B + b0 + tid] = gene;    // coalesced
}

// ---------------------------------------------------------------------------
// Kernel 2: predictor (unchanged; ~10-15 us, not the bottleneck).
// ---------------------------------------------------------------------------
__global__ __launch_bounds__(128) void pred_kernel(
    const float* __restrict__ glT, const float* __restrict__ Wp1,
    const float* __restrict__ bp1, const float* __restrict__ Wp2,
    const float* __restrict__ bp2, float* __restrict__ out)
{
    __shared__ float sgl[8 * G];     // [b_local][g], 4 KiB
    __shared__ float sred[2][8];

    const int tid = threadIdx.x;     // j = tid
    const int b0  = blockIdx.x * 8;

    {
        const float4* gp = (const float4*)(glT + (size_t)tid * B + b0);
        const float4 v0 = gp[0], v1 = gp[1];
        sgl[0 * G + tid] = v0.x; sgl[1 * G + tid] = v0.y;
        sgl[2 * G + tid] = v0.z; sgl[3 * G + tid] = v0.w;
        sgl[4 * G + tid] = v1.x; sgl[5 * G + tid] = v1.y;
        sgl[6 * G + tid] = v1.z; sgl[7 * G + tid] = v1.w;
    }

    const bool  jv   = (tid < PH);
    const float bpj  = jv ? bp1[tid] : 0.f;
    const float wp2j = jv ? Wp2[tid] : 0.f;
    __syncthreads();

    float acc[8];
    #pragma unroll
    for (int b = 0; b < 8; b++) acc[b] = bpj;

    const float2* sgl2 = (const float2*)sgl;
    #pragma unroll
    for (int gc = 0; gc < 4; gc++) {
        float2 w[16];
        #pragma unroll
        for (int p = 0; p < 16; p++) {
            const int gg = gc * 32 + 2 * p;
            w[p].x = jv ? Wp1[(size_t)gg * PH + tid]       : 0.f;
            w[p].y = jv ? Wp1[(size_t)(gg + 1) * PH + tid] : 0.f;
        }
        #pragma unroll
        for (int b = 0; b < 8; b++) {
            float a = acc[b];
            #pragma unroll
            for (int p = 0; p < 16; p++) {
                const float2 s2 = sgl2[b * (G / 2) + gc * 16 + p];
                a = fmaf(w[p].x, s2.x, a);
                a = fmaf(w[p].y, s2.y, a);
            }
            acc[b] = a;
        }
    }

    const int lane = tid & 63;
    const int wv   = tid >> 6;
    #pragma unroll
    for (int b = 0; b < 8; b++) {
        float v = fmaxf(acc[b], 0.f) * wp2j;
        #pragma unroll
        for (int off = 32; off > 0; off >>= 1) v += __shfl_down(v, off, 64);
        if (lane == 0) sred[wv][b] = v;
    }
    __syncthreads();
    if (tid < 8) out[b0 + tid] = sred[0][tid] + sred[1][tid] + bp2[0];
}

extern "C" void kernel_launch(void* const* d_in, const int* in_sizes, int n_in,
                              void* d_out, int out_size, void* d_ws, size_t ws_size,
                              hipStream_t stream) {
    const float* x   = (const float*)d_in[0];
    const float* W1  = (const float*)d_in[1];
    const float* b1  = (const float*)d_in[2];
    const float* W2  = (const float*)d_in[3];
    const float* b2  = (const float*)d_in[4];
    const float* Wp1 = (const float*)d_in[5];
    const float* bp1 = (const float*)d_in[6];
    const float* Wp2 = (const float*)d_in[7];
    const float* bp2 = (const float*)d_in[8];
    float* out = (float*)d_out;
    float* glT = (float*)d_ws;   // G*B floats = 8 MiB scratch

    gene_kernel<<<dim3(B / 256, G), 256, 0, stream>>>(x, W1, b1, W2, b2, glT);
    pred_kernel<<<dim3(B / 8), 128, 0, stream>>>(glT, Wp1, bp1, Wp2, bp2, out);
}